// Round 6
// baseline (64.020 us; speedup 1.0000x reference)
//
#include <hip/hip_runtime.h>

namespace {

constexpr int NROI  = 256;
constexpr int C     = 256;
constexpr int PHh   = 8;
constexpr int PWw   = 32;
constexpr int NI    = 4;
constexpr int CHUNK = 32;             // channels per block
constexpr int WP_MAX = 80;            // max x-span (mapped roi width <= 72 by geometry)
constexpr int G1P   = 4 * WP_MAX;     // float2 pairs per buffer (4 sample rows/wave)
constexpr int KMAXD = (2 * G1P + 63) / 64;   // 10 dword staging ops max

typedef __attribute__((ext_vector_type(2))) float f32x2;

// s_waitcnt immediate: wait vmcnt<=vm (gfx9: vm[3:0]@[3:0], vm[5:4]@[15:14]; exp/lgkm ignored)
__host__ __device__ constexpr unsigned wimm(unsigned vm) {
    return (vm & 0xFu) | (0x7u << 4) | (0xFu << 8) | (((vm >> 4) & 0x3u) << 14);
}

__device__ __forceinline__ void interp_weights(float c, int size,
                                               int& lo, int& hi,
                                               float& w0, float& w1)
{
    bool  valid = (c >= -1.0f) && (c <= (float)size);
    float cc    = fmaxf(c, 0.0f);
    int   low   = (int)floorf(cc);
    bool  atedge = (low >= size - 1);
    low = min(low, size - 1);
    int   high  = min(low + 1, size - 1);
    float frac  = atedge ? 0.0f : (cc - (float)low);
    float v     = valid ? 1.0f : 0.0f;
    lo = low; hi = high;
    w0 = (1.0f - frac) * v;
    w1 = frac * v;
}

// Depth-2 per-wave pipeline; K width-4 global_load_lds ops stage the y-pair-packed
// G1 buffer (float2 {F[ylo],F[yhi]} per (sample_row, x)). Taps become ds_read_b64.
// vmcnt ledger (in-order VMEM): steady wait 2K+8 leaves {stage cc+1, stage cc+2,
// stores cc-2, stores cc-1} in flight, stage cc drained. Stores never waited on.
// Output stores NON-TEMPORAL: write-once stream must not evict L3-resident features.
template<int K>
__device__ __forceinline__ void run_staged(
    const float* __restrict__ base, int HW,
    float* b0, float* b1, float* b2,
    const int (&gofs)[KMAXD],
    const int (&toff2)[8], const float (&twt)[16], const float (&m)[NI],
    float* __restrict__ ob)
{
    auto stage = [&](int ch, float* dst) {
        const float* g = base + (size_t)ch * HW;
        #pragma unroll
        for (int j = 0; j < K; ++j)
            __builtin_amdgcn_global_load_lds(
                (const __attribute__((address_space(1))) void*)(g + gofs[j]),
                (__attribute__((address_space(3))) void*)(dst + j * 64),
                4, 0, 0);
    };
    auto compute = [&](int cc, const float* lp) {
        const f32x2* lp2 = (const f32x2*)lp;
        float acc = 0.0f;
        #pragma unroll
        for (int t = 0; t < 4; ++t) {
            f32x2 vl = lp2[toff2[2 * t]];
            f32x2 vh = lp2[toff2[2 * t + 1]];
            acc = fmaf(twt[4 * t + 0], vl.x, acc);
            acc = fmaf(twt[4 * t + 1], vl.y, acc);
            acc = fmaf(twt[4 * t + 2], vh.x, acc);
            acc = fmaf(twt[4 * t + 3], vh.y, acc);
        }
        #pragma unroll
        for (int i = 0; i < NI; ++i)
            __builtin_nontemporal_store(acc * m[i],
                &ob[(size_t)((i * C + cc) * (PHh * PWw))]);
    };

    // prologue: two channels in flight, then start the third
    stage(0, b0); stage(1, b1); stage(2, b2);
    __builtin_amdgcn_s_waitcnt(wimm(2 * K));       // stage0 drained
    __builtin_amdgcn_sched_barrier(0);
    compute(0, b0);
    stage(3, b0);
    __builtin_amdgcn_s_waitcnt(wimm(2 * K + 4));   // stage1 drained
    __builtin_amdgcn_sched_barrier(0);
    compute(1, b1);

    float* r0 = b2;  // holds ch cc
    float* r1 = b0;  // holds ch cc+1
    float* r2 = b1;  // free -> stage target for ch cc+2
    #pragma unroll 1
    for (int cc = 2; cc < CHUNK - 2; ++cc) {
        stage(cc + 2, r2);
        __builtin_amdgcn_s_waitcnt(wimm(2 * K + 8));
        __builtin_amdgcn_sched_barrier(0);
        compute(cc, r0);
        float* t = r0; r0 = r1; r1 = r2; r2 = t;
    }
    __builtin_amdgcn_s_waitcnt(wimm(K + 8));
    __builtin_amdgcn_sched_barrier(0);
    compute(CHUNK - 2, r0);
    __builtin_amdgcn_s_waitcnt(wimm(8));
    __builtin_amdgcn_sched_barrier(0);
    compute(CHUNK - 1, r1);
}

__global__ __launch_bounds__(256) void mia_kernel(
    const float* __restrict__ f0, const float* __restrict__ f1,
    const float* __restrict__ f2, const float* __restrict__ f3,
    const float* __restrict__ rois, float* __restrict__ out)
{
    const int n   = blockIdx.x;
    const int c0  = blockIdx.y * CHUNK;
    const int tid = threadIdx.x;

    __shared__ float sroi[NI * 5];
    __shared__ int   s_ylo[16], s_yhi[16], s_xlo[64], s_xhi[64];
    __shared__ float s_wy0[16], s_wy1[16], s_wx0[64], s_wx1[64];
    __shared__ __align__(16) float wbuf[4][3][2 * G1P];

    if (tid < NI * 5) sroi[tid] = rois[n * (NI * 5) + tid];
    __syncthreads();

    const float bx1 = fminf(fminf(sroi[1],  sroi[6]),  fminf(sroi[11], sroi[16]));
    const float by1 = fminf(fminf(sroi[2],  sroi[7]),  fminf(sroi[12], sroi[17]));
    const float bx2 = fmaxf(fmaxf(sroi[3],  sroi[8]),  fmaxf(sroi[13], sroi[18]));
    const float by2 = fmaxf(fmaxf(sroi[4],  sroi[9]),  fmaxf(sroi[14], sroi[19]));
    const float brw = bx2 - bx1, brh = by2 - by1;

    const float s    = sqrtf(brh * brw);
    const float lv   = floorf(4.0f + log2f(s / 224.0f + 1e-6f));
    const int   level = (int)(fminf(fmaxf(lv, 2.0f), 5.0f)) - 2;

    const float* feat = (level == 0) ? f0 : (level == 1) ? f1 : (level == 2) ? f2 : f3;
    const int   FS    = 256 >> level;
    const float scale = 1.0f / (float)(4 << level);
    const int   bid   = (int)sroi[0];

    const float x1 = bx1 * scale, y1 = by1 * scale;
    const float roi_w = fmaxf(bx2 * scale - x1, 1.0f);
    const float roi_h = fmaxf(by2 * scale - y1, 1.0f);

    if (tid < 16) {
        float bin = roi_h / 16.0f;
        float cy  = y1 + ((float)tid + 0.5f) * bin;
        interp_weights(cy, FS, s_ylo[tid], s_yhi[tid], s_wy0[tid], s_wy1[tid]);
    } else if (tid >= 64 && tid < 128) {
        int   q   = tid - 64;
        float bin = roi_w / 64.0f;
        float cx  = x1 + ((float)q + 0.5f) * bin;
        interp_weights(cx, FS, s_xlo[q], s_xhi[q], s_wx0[q], s_wx1[q]);
    }
    __syncthreads();

    const int ph = tid >> 5, pw = tid & 31;
    const int w  = tid >> 6;                 // wave id: owns output rows 2w, 2w+1

    float m[NI];
    {
        const float wr = (float)PWw / brw;
        const float hr = (float)PHh / brh;
        #pragma unroll
        for (int i = 0; i < NI; ++i) {
            int px0  = (int)((sroi[i * 5 + 1] - bx1) * wr);
            int py1_ = (int)((sroi[i * 5 + 2] - by1) * hr);
            int px2  = (int)((sroi[i * 5 + 3] - bx1) * wr);
            int py3_ = (int)((sroi[i * 5 + 4] - by1) * hr);
            m[i] = (ph >= py1_ && ph < py3_ && pw >= px0 && pw < px2) ? 1.0f : 0.0f;
        }
    }

    const int    HW   = FS * FS;
    const float* base = feat + (size_t)(bid * C + c0) * HW;
    float*       ob   = out + ((size_t)(n * NI) * C + c0) * (PHh * PWw) + tid;

    const int x0 = s_xlo[0];
    const int Wp = s_xhi[63] - x0 + 1;       // x-span; <= 72 by level geometry

    if (Wp <= WP_MAX) {
        // G1 buffer: for wave's 4 sample rows srl=0..3, pairs {F[ylo],F[yhi]} per x.
        const int Nd = 8 * Wp;               // dwords per channel = 4 rows * Wp * 2
        const int K  = (Nd + 63) >> 6;

        // staging source offsets: LDS dword d (linear dest) <- decoded (srl, x, lo/hi)
        int gofs[KMAXD];
        const float rcpW = 1.0f / (float)Wp;
        #pragma unroll
        for (int j = 0; j < KMAXD; ++j) {
            if (j < K) {
                int d = (tid & 63) + j * 64;
                if (d >= Nd) d = Nd - 1;     // clamp: duplicate value, dest stays linear
                int pr = d >> 1, p = d & 1;
                int srl = (int)((float)pr * rcpW);
                int x   = pr - srl * Wp;
                if (x < 0)        { --srl; x += Wp; }
                else if (x >= Wp) { ++srl; x -= Wp; }
                int srg = 4 * w + srl;
                int row = p ? s_yhi[srg] : s_ylo[srg];
                gofs[j] = row * FS + x0 + x;
            } else gofs[j] = 0;
        }

        // per-thread: 8 float2 offsets + 16 weights (0.25 sample-mean folded)
        int   toff2[8];
        float twt[16];
        #pragma unroll
        for (int dr = 0; dr < 2; ++dr) {
            int   sr  = 2 * ph + dr;
            int   srl = sr - 4 * w;
            float wy0 = s_wy0[sr] * 0.25f, wy1 = s_wy1[sr] * 0.25f;
            #pragma unroll
            for (int dq = 0; dq < 2; ++dq) {
                int q = 2 * pw + dq;
                int t = dr * 2 + dq;
                toff2[2 * t]     = srl * Wp + (s_xlo[q] - x0);
                toff2[2 * t + 1] = srl * Wp + (s_xhi[q] - x0);
                float wx0 = s_wx0[q], wx1 = s_wx1[q];
                twt[4 * t + 0] = wy0 * wx0;
                twt[4 * t + 1] = wy1 * wx0;
                twt[4 * t + 2] = wy0 * wx1;
                twt[4 * t + 3] = wy1 * wx1;
            }
        }

        float* b0 = &wbuf[w][0][0];
        float* b1 = &wbuf[w][1][0];
        float* b2 = &wbuf[w][2][0];

        switch (K) {
            case 1:  run_staged<1 >(base, HW, b0, b1, b2, gofs, toff2, twt, m, ob); break;
            case 2:  run_staged<2 >(base, HW, b0, b1, b2, gofs, toff2, twt, m, ob); break;
            case 3:  run_staged<3 >(base, HW, b0, b1, b2, gofs, toff2, twt, m, ob); break;
            case 4:  run_staged<4 >(base, HW, b0, b1, b2, gofs, toff2, twt, m, ob); break;
            case 5:  run_staged<5 >(base, HW, b0, b1, b2, gofs, toff2, twt, m, ob); break;
            case 6:  run_staged<6 >(base, HW, b0, b1, b2, gofs, toff2, twt, m, ob); break;
            case 7:  run_staged<7 >(base, HW, b0, b1, b2, gofs, toff2, twt, m, ob); break;
            case 8:  run_staged<8 >(base, HW, b0, b1, b2, gofs, toff2, twt, m, ob); break;
            case 9:  run_staged<9 >(base, HW, b0, b1, b2, gofs, toff2, twt, m, ob); break;
            default: run_staged<10>(base, HW, b0, b1, b2, gofs, toff2, twt, m, ob); break;
        }
    } else {
        // fallback: direct per-thread gather (should not trigger; wave-uniform branch)
        int   gidx[16];
        float tw[16];
        {
            int k = 0;
            #pragma unroll
            for (int sr = 0; sr < 2; ++sr) {
                int   r   = 2 * ph + sr;
                int   ylo = s_ylo[r], yhi = s_yhi[r];
                float wy0 = s_wy0[r] * 0.25f, wy1 = s_wy1[r] * 0.25f;
                #pragma unroll
                for (int sc = 0; sc < 2; ++sc) {
                    int   q   = 2 * pw + sc;
                    int   xlo = s_xlo[q], xhi = s_xhi[q];
                    float wx0 = s_wx0[q], wx1 = s_wx1[q];
                    gidx[k] = ylo * FS + xlo; tw[k] = wy0 * wx0; ++k;
                    gidx[k] = ylo * FS + xhi; tw[k] = wy0 * wx1; ++k;
                    gidx[k] = yhi * FS + xlo; tw[k] = wy1 * wx0; ++k;
                    gidx[k] = yhi * FS + xhi; tw[k] = wy1 * wx1; ++k;
                }
            }
        }
        for (int cc = 0; cc < CHUNK; ++cc) {
            const float* p = base + (size_t)cc * HW;
            float acc = 0.0f;
            #pragma unroll
            for (int k = 0; k < 16; ++k) acc = fmaf(tw[k], p[gidx[k]], acc);
            #pragma unroll
            for (int i = 0; i < NI; ++i)
                __builtin_nontemporal_store(acc * m[i],
                    &ob[(size_t)((i * C + cc) * (PHh * PWw))]);
        }
    }
}

} // namespace

extern "C" void kernel_launch(void* const* d_in, const int* in_sizes, int n_in,
                              void* d_out, int out_size, void* d_ws, size_t ws_size,
                              hipStream_t stream)
{
    const float* f0   = (const float*)d_in[0];
    const float* f1   = (const float*)d_in[1];
    const float* f2   = (const float*)d_in[2];
    const float* f3   = (const float*)d_in[3];
    const float* rois = (const float*)d_in[4];
    float*       out  = (float*)d_out;

    dim3 grid(NROI, C / CHUNK);
    mia_kernel<<<grid, 256, 0, stream>>>(f0, f1, f2, f3, rois, out);
}

// Round 7
// 63.266 us; speedup vs baseline: 1.0119x; 1.0119x over previous
//
#include <hip/hip_runtime.h>

namespace {

constexpr int C     = 256;
constexpr int PHh   = 8;
constexpr int PWw   = 32;
constexpr int NI    = 4;
constexpr int CHUNK = 32;          // channels per block
constexpr int SLAB4_MAX = 512;     // per-wave padded slab budget (floats)

// s_waitcnt immediate: wait vmcnt<=vm (gfx9: vm[3:0]@[3:0], vm[5:4]@[15:14]; exp/lgkm ignored)
__host__ __device__ constexpr unsigned wimm(unsigned vm) {
    return (vm & 0xFu) | (0x7u << 4) | (0xFu << 8) | (((vm >> 4) & 0x3u) << 14);
}

__device__ __forceinline__ void interp_weights(float c, int size,
                                               int& lo, int& hi,
                                               float& w0, float& w1)
{
    bool  valid = (c >= -1.0f) && (c <= (float)size);
    float cc    = fmaxf(c, 0.0f);
    int   low   = (int)floorf(cc);
    bool  atedge = (low >= size - 1);
    low = min(low, size - 1);
    int   high  = min(low + 1, size - 1);
    float frac  = atedge ? 0.0f : (cc - (float)low);
    float v     = valid ? 1.0f : 0.0f;
    lo = low; hi = high;
    w0 = (1.0f - frac) * v;
    w1 = frac * v;
}

// Depth-2 single-wave pipeline; K4 width-16 global_load_lds ops per channel.
// vmcnt ledger (in-order VMEM): steady wait 2*K4+8 leaves {stage cc+1, stage cc+2,
// 8 younger stores} in flight; compute(cc)'s buffer always drained. Stores are
// never waited on. Output stores NON-TEMPORAL (write-once stream; keep L3 for
// the feature maps).
template<int K4>
__device__ __forceinline__ void run_staged(
    const float* __restrict__ base, int HW,
    float* b0, float* b1, float* b2,
    const int (&gofs)[2], const int (&toff)[16],
    const float (&tw)[16], const float (&m)[NI],
    float* __restrict__ ob)
{
    auto stage = [&](int ch, float* dst) {
        const float* g = base + (size_t)ch * HW;
        #pragma unroll
        for (int j = 0; j < K4; ++j)
            __builtin_amdgcn_global_load_lds(
                (const __attribute__((address_space(1))) void*)(g + gofs[j]),
                (__attribute__((address_space(3))) void*)(dst + j * 256),
                16, 0, 0);
    };
    auto compute = [&](int cc, const float* lp) {
        float acc = 0.0f;
        #pragma unroll
        for (int k = 0; k < 16; ++k) acc = fmaf(tw[k], lp[toff[k]], acc);
        #pragma unroll
        for (int i = 0; i < NI; ++i)
            __builtin_nontemporal_store(acc * m[i],
                &ob[(size_t)((i * C + cc) * (PHh * PWw))]);
    };

    // prologue: two channels in flight, then start the third
    stage(0, b0); stage(1, b1); stage(2, b2);
    __builtin_amdgcn_s_waitcnt(wimm(2 * K4));      // stage0 drained
    __builtin_amdgcn_sched_barrier(0);
    compute(0, b0);
    stage(3, b0);
    __builtin_amdgcn_s_waitcnt(wimm(2 * K4 + 4));  // stage1 drained
    __builtin_amdgcn_sched_barrier(0);
    compute(1, b1);

    float* r0 = b2;  // holds ch cc
    float* r1 = b0;  // holds ch cc+1
    float* r2 = b1;  // free -> stage target for ch cc+2
    #pragma unroll 1
    for (int cc = 2; cc < CHUNK - 2; ++cc) {
        stage(cc + 2, r2);
        __builtin_amdgcn_s_waitcnt(wimm(2 * K4 + 8));
        __builtin_amdgcn_sched_barrier(0);
        compute(cc, r0);
        float* t = r0; r0 = r1; r1 = r2; r2 = t;
    }
    __builtin_amdgcn_s_waitcnt(wimm(K4 + 8));
    __builtin_amdgcn_sched_barrier(0);
    compute(CHUNK - 2, r0);
    __builtin_amdgcn_s_waitcnt(wimm(8));
    __builtin_amdgcn_sched_barrier(0);
    compute(CHUNK - 1, r1);
}

// One wave (64 threads) per block: owns output row-pair rp of one (roi, chunk).
__global__ __launch_bounds__(64) void mia_kernel(
    const float* __restrict__ f0, const float* __restrict__ f1,
    const float* __restrict__ f2, const float* __restrict__ f3,
    const float* __restrict__ rois, float* __restrict__ out)
{
    const int n    = blockIdx.x;
    const int c0   = blockIdx.y * CHUNK;
    const int rp   = blockIdx.z;          // row pair: output rows 2rp, 2rp+1
    const int lane = threadIdx.x;

    __shared__ float sroi[NI * 5];
    __shared__ int   s_ylo[4], s_yhi[4], s_xlo[64], s_xhi[64];
    __shared__ float s_wy0[4], s_wy1[4], s_wx0[64], s_wx1[64];
    __shared__ __align__(16) float wbuf[3][SLAB4_MAX];

    if (lane < NI * 5) sroi[lane] = rois[n * (NI * 5) + lane];
    __syncthreads();

    const float bx1 = fminf(fminf(sroi[1],  sroi[6]),  fminf(sroi[11], sroi[16]));
    const float by1 = fminf(fminf(sroi[2],  sroi[7]),  fminf(sroi[12], sroi[17]));
    const float bx2 = fmaxf(fmaxf(sroi[3],  sroi[8]),  fmaxf(sroi[13], sroi[18]));
    const float by2 = fmaxf(fmaxf(sroi[4],  sroi[9]),  fmaxf(sroi[14], sroi[19]));
    const float brw = bx2 - bx1, brh = by2 - by1;

    const float s    = sqrtf(brh * brw);
    const float lv   = floorf(4.0f + log2f(s / 224.0f + 1e-6f));
    const int   level = (int)(fminf(fmaxf(lv, 2.0f), 5.0f)) - 2;

    const float* feat = (level == 0) ? f0 : (level == 1) ? f1 : (level == 2) ? f2 : f3;
    const int   FS    = 256 >> level;
    const float scale = 1.0f / (float)(4 << level);
    const int   bid   = (int)sroi[0];

    const float x1 = bx1 * scale, y1 = by1 * scale;
    const float roi_w = fmaxf(bx2 * scale - x1, 1.0f);
    const float roi_h = fmaxf(by2 * scale - y1, 1.0f);

    // col table: lane q = lane (all 64 sample cols)
    {
        float bin = roi_w / 64.0f;
        float cx  = x1 + ((float)lane + 0.5f) * bin;
        interp_weights(cx, FS, s_xlo[lane], s_xhi[lane], s_wx0[lane], s_wx1[lane]);
    }
    // row table: this wave's 4 sample rows (global rows 4rp..4rp+3)
    if (lane < 4) {
        int   r   = 4 * rp + lane;
        float bin = roi_h / 16.0f;
        float cy  = y1 + ((float)r + 0.5f) * bin;
        interp_weights(cy, FS, s_ylo[lane], s_yhi[lane], s_wy0[lane], s_wy1[lane]);
    }
    __syncthreads();

    const int ph = 2 * rp + (lane >> 5), pw = lane & 31;

    // 16 taps (feature row/col + weight, 0.25 sample-mean folded); local row idx
    int   fr[16], fc[16];
    float tw[16];
    {
        int k = 0;
        #pragma unroll
        for (int sr = 0; sr < 2; ++sr) {
            int   lr  = 2 * (lane >> 5) + sr;         // local row table index 0..3
            int   ylo = s_ylo[lr], yhi = s_yhi[lr];
            float wy0 = s_wy0[lr] * 0.25f, wy1 = s_wy1[lr] * 0.25f;
            #pragma unroll
            for (int sc = 0; sc < 2; ++sc) {
                int   q   = 2 * pw + sc;
                int   xlo = s_xlo[q], xhi = s_xhi[q];
                float wx0 = s_wx0[q], wx1 = s_wx1[q];
                fr[k] = ylo; fc[k] = xlo; tw[k] = wy0 * wx0; ++k;
                fr[k] = ylo; fc[k] = xhi; tw[k] = wy0 * wx1; ++k;
                fr[k] = yhi; fc[k] = xlo; tw[k] = wy1 * wx0; ++k;
                fr[k] = yhi; fc[k] = xhi; tw[k] = wy1 * wx1; ++k;
            }
        }
    }

    float m[NI];
    {
        const float wr = (float)PWw / brw;
        const float hr = (float)PHh / brh;
        #pragma unroll
        for (int i = 0; i < NI; ++i) {
            int px0  = (int)((sroi[i * 5 + 1] - bx1) * wr);
            int py1_ = (int)((sroi[i * 5 + 2] - by1) * hr);
            int px2  = (int)((sroi[i * 5 + 3] - bx1) * wr);
            int py3_ = (int)((sroi[i * 5 + 4] - by1) * hr);
            m[i] = (ph >= py1_ && ph < py3_ && pw >= px0 && pw < px2) ? 1.0f : 0.0f;
        }
    }

    const int    HW   = FS * FS;
    const float* base = feat + (size_t)(bid * C + c0) * HW;
    float*       ob   = out + ((size_t)(n * NI) * C + c0) * (PHh * PWw)
                            + ph * PWw + pw;

    // wave slab: feature rows for its 4 sample rows; x-range padded to 16B groups.
    // FS % 4 == 0 and x0a % 4 == 0  =>  x0a + Wp4 <= FS (no row overrun).
    const int x0     = s_xlo[0];
    const int x0a    = x0 & ~3;
    const int xend   = s_xhi[63] + 1;
    const int Wp4    = (xend - x0a + 3) & ~3;
    const int slabY0 = s_ylo[0];
    const int rowsW  = s_yhi[3] - slabY0 + 1;
    const int slabN4 = rowsW * Wp4;

    if (slabN4 <= SLAB4_MAX) {
        const int K4 = (slabN4 + 255) >> 8;
        const int W4 = Wp4 >> 2;                // 16B groups per row

        int gofs[2];
        {
            const int gmax = (slabN4 >> 2) - 1;
            #pragma unroll
            for (int j = 0; j < 2; ++j) {
                int g = lane + j * 64;
                if (g > gmax) g = gmax;          // clamp: duplicate group, dest stays linear
                int row  = g / W4;
                int col4 = g - row * W4;
                gofs[j] = (slabY0 + row) * FS + x0a + (col4 << 2);
            }
        }

        int toff[16];
        #pragma unroll
        for (int k = 0; k < 16; ++k)
            toff[k] = (fr[k] - slabY0) * Wp4 + (fc[k] - x0a);

        if (K4 == 1) run_staged<1>(base, HW, &wbuf[0][0], &wbuf[1][0], &wbuf[2][0],
                                   gofs, toff, tw, m, ob);
        else         run_staged<2>(base, HW, &wbuf[0][0], &wbuf[1][0], &wbuf[2][0],
                                   gofs, toff, tw, m, ob);
    } else {
        // fallback: direct per-thread gather (rare; wave-uniform branch)
        int gidx[16];
        #pragma unroll
        for (int k = 0; k < 16; ++k) gidx[k] = fr[k] * FS + fc[k];

        for (int cc = 0; cc < CHUNK; ++cc) {
            const float* p = base + (size_t)cc * HW;
            float acc = 0.0f;
            #pragma unroll
            for (int k = 0; k < 16; ++k) acc = fmaf(tw[k], p[gidx[k]], acc);
            #pragma unroll
            for (int i = 0; i < NI; ++i)
                __builtin_nontemporal_store(acc * m[i],
                    &ob[(size_t)((i * C + cc) * (PHh * PWw))]);
        }
    }
}

} // namespace

extern "C" void kernel_launch(void* const* d_in, const int* in_sizes, int n_in,
                              void* d_out, int out_size, void* d_ws, size_t ws_size,
                              hipStream_t stream)
{
    const float* f0   = (const float*)d_in[0];
    const float* f1   = (const float*)d_in[1];
    const float* f2   = (const float*)d_in[2];
    const float* f3   = (const float*)d_in[3];
    const float* rois = (const float*)d_in[4];
    float*       out  = (float*)d_out;

    const int nroi = in_sizes[4] / (NI * 5);
    dim3 grid(nroi, C / CHUNK, PHh / 2);
    mia_kernel<<<grid, 64, 0, stream>>>(f0, f1, f2, f3, rois, out);
}

// Round 8
// 61.411 us; speedup vs baseline: 1.0425x; 1.0302x over previous
//
#include <hip/hip_runtime.h>

namespace {

constexpr int NROI  = 256;
constexpr int C     = 256;
constexpr int PHh   = 8;
constexpr int PWw   = 32;
constexpr int NI    = 4;
constexpr int CHUNK = 32;          // channels per block
constexpr int SLAB4_MAX = 512;     // per-wave padded slab budget (floats, mult of 256)

// s_waitcnt immediate: wait vmcnt<=vm (gfx9: vm[3:0]@[3:0], vm[5:4]@[15:14]; exp/lgkm ignored)
__host__ __device__ constexpr unsigned wimm(unsigned vm) {
    return (vm & 0xFu) | (0x7u << 4) | (0xFu << 8) | (((vm >> 4) & 0x3u) << 14);
}

__device__ __forceinline__ void interp_weights(float c, int size,
                                               int& lo, int& hi,
                                               float& w0, float& w1)
{
    bool  valid = (c >= -1.0f) && (c <= (float)size);
    float cc    = fmaxf(c, 0.0f);
    int   low   = (int)floorf(cc);
    bool  atedge = (low >= size - 1);
    low = min(low, size - 1);
    int   high  = min(low + 1, size - 1);
    float frac  = atedge ? 0.0f : (cc - (float)low);
    float v     = valid ? 1.0f : 0.0f;
    lo = low; hi = high;
    w0 = (1.0f - frac) * v;
    w1 = frac * v;
}

// Depth-2 per-wave channel pipeline; K4 width-16 staging ops per channel.
// vmcnt ledger (in-order VMEM): steady-state wait 2*K4+8 leaves
//   {stage cc+1, stage cc+2, stores cc-2, stores cc-1} in flight, stage cc drained.
// Output stores are NON-TEMPORAL: write-once stream must not evict the
// feature maps from Infinity Cache.
template<int K4>
__device__ __forceinline__ void run_staged(
    const float* __restrict__ base, int HW,
    float* b0, float* b1, float* b2,
    const int (&gofs)[2], const int (&toff)[16],
    const float (&tw)[16], const float (&m)[NI],
    float* __restrict__ ob)
{
    auto stage = [&](int ch, float* dst) {
        const float* g = base + (size_t)ch * HW;
        #pragma unroll
        for (int j = 0; j < K4; ++j)
            __builtin_amdgcn_global_load_lds(
                (const __attribute__((address_space(1))) void*)(g + gofs[j]),
                (__attribute__((address_space(3))) void*)(dst + j * 256),
                16, 0, 0);
    };
    auto compute = [&](int cc, const float* lp) {
        float acc = 0.0f;
        #pragma unroll
        for (int k = 0; k < 16; ++k) acc = fmaf(tw[k], lp[toff[k]], acc);
        #pragma unroll
        for (int i = 0; i < NI; ++i)
            __builtin_nontemporal_store(acc * m[i],
                &ob[(size_t)((i * C + cc) * (PHh * PWw))]);
    };

    // prologue: two channels in flight, then start the third
    stage(0, b0); stage(1, b1); stage(2, b2);
    __builtin_amdgcn_s_waitcnt(wimm(2 * K4));      // stage0 drained
    __builtin_amdgcn_sched_barrier(0);
    compute(0, b0);
    stage(3, b0);
    __builtin_amdgcn_s_waitcnt(wimm(2 * K4 + 4));  // stage1 drained
    __builtin_amdgcn_sched_barrier(0);
    compute(1, b1);

    float* r0 = b2;  // holds ch cc
    float* r1 = b0;  // holds ch cc+1
    float* r2 = b1;  // free -> stage target for ch cc+2
    #pragma unroll 1
    for (int cc = 2; cc < CHUNK - 2; ++cc) {
        stage(cc + 2, r2);
        __builtin_amdgcn_s_waitcnt(wimm(2 * K4 + 8));
        __builtin_amdgcn_sched_barrier(0);
        compute(cc, r0);
        float* t = r0; r0 = r1; r1 = r2; r2 = t;
    }
    __builtin_amdgcn_s_waitcnt(wimm(K4 + 8));
    __builtin_amdgcn_sched_barrier(0);
    compute(CHUNK - 2, r0);
    __builtin_amdgcn_s_waitcnt(wimm(8));
    __builtin_amdgcn_sched_barrier(0);
    compute(CHUNK - 1, r1);
}

__global__ __launch_bounds__(256) void mia_kernel(
    const float* __restrict__ f0, const float* __restrict__ f1,
    const float* __restrict__ f2, const float* __restrict__ f3,
    const float* __restrict__ rois, float* __restrict__ out)
{
    const int n   = blockIdx.x;
    const int c0  = blockIdx.y * CHUNK;
    const int tid = threadIdx.x;

    __shared__ float sroi[NI * 5];
    __shared__ int   s_ylo[16], s_yhi[16], s_xlo[64], s_xhi[64];
    __shared__ float s_wy0[16], s_wy1[16], s_wx0[64], s_wx1[64];
    __shared__ __align__(16) float wbuf[4][3][SLAB4_MAX];

    if (tid < NI * 5) sroi[tid] = rois[n * (NI * 5) + tid];
    __syncthreads();

    const float bx1 = fminf(fminf(sroi[1],  sroi[6]),  fminf(sroi[11], sroi[16]));
    const float by1 = fminf(fminf(sroi[2],  sroi[7]),  fminf(sroi[12], sroi[17]));
    const float bx2 = fmaxf(fmaxf(sroi[3],  sroi[8]),  fmaxf(sroi[13], sroi[18]));
    const float by2 = fmaxf(fmaxf(sroi[4],  sroi[9]),  fmaxf(sroi[14], sroi[19]));
    const float brw = bx2 - bx1, brh = by2 - by1;

    const float s    = sqrtf(brh * brw);
    const float lv   = floorf(4.0f + log2f(s / 224.0f + 1e-6f));
    const int   level = (int)(fminf(fmaxf(lv, 2.0f), 5.0f)) - 2;

    const float* feat = (level == 0) ? f0 : (level == 1) ? f1 : (level == 2) ? f2 : f3;
    const int   FS    = 256 >> level;
    const float scale = 1.0f / (float)(4 << level);
    const int   bid   = (int)sroi[0];

    const float x1 = bx1 * scale, y1 = by1 * scale;
    const float roi_w = fmaxf(bx2 * scale - x1, 1.0f);
    const float roi_h = fmaxf(by2 * scale - y1, 1.0f);

    if (tid < 16) {
        float bin = roi_h / 16.0f;
        float cy  = y1 + ((float)tid + 0.5f) * bin;
        interp_weights(cy, FS, s_ylo[tid], s_yhi[tid], s_wy0[tid], s_wy1[tid]);
    } else if (tid >= 64 && tid < 128) {
        int   q   = tid - 64;
        float bin = roi_w / 64.0f;
        float cx  = x1 + ((float)q + 0.5f) * bin;
        interp_weights(cx, FS, s_xlo[q], s_xhi[q], s_wx0[q], s_wx1[q]);
    }
    __syncthreads();

    const int ph = tid >> 5, pw = tid & 31;
    const int w  = tid >> 6;                 // wave id: owns output rows 2w, 2w+1

    // 16 taps (feature row/col + weight, 0.25 sample-mean folded)
    int   fr[16], fc[16];
    float tw[16];
    {
        int k = 0;
        #pragma unroll
        for (int sr = 0; sr < 2; ++sr) {
            int   r   = 2 * ph + sr;
            int   ylo = s_ylo[r], yhi = s_yhi[r];
            float wy0 = s_wy0[r] * 0.25f, wy1 = s_wy1[r] * 0.25f;
            #pragma unroll
            for (int sc = 0; sc < 2; ++sc) {
                int   q   = 2 * pw + sc;
                int   xlo = s_xlo[q], xhi = s_xhi[q];
                float wx0 = s_wx0[q], wx1 = s_wx1[q];
                fr[k] = ylo; fc[k] = xlo; tw[k] = wy0 * wx0; ++k;
                fr[k] = ylo; fc[k] = xhi; tw[k] = wy0 * wx1; ++k;
                fr[k] = yhi; fc[k] = xlo; tw[k] = wy1 * wx0; ++k;
                fr[k] = yhi; fc[k] = xhi; tw[k] = wy1 * wx1; ++k;
            }
        }
    }

    float m[NI];
    {
        const float wr = (float)PWw / brw;
        const float hr = (float)PHh / brh;
        #pragma unroll
        for (int i = 0; i < NI; ++i) {
            int px0  = (int)((sroi[i * 5 + 1] - bx1) * wr);
            int py1_ = (int)((sroi[i * 5 + 2] - by1) * hr);
            int px2  = (int)((sroi[i * 5 + 3] - bx1) * wr);
            int py3_ = (int)((sroi[i * 5 + 4] - by1) * hr);
            m[i] = (ph >= py1_ && ph < py3_ && pw >= px0 && pw < px2) ? 1.0f : 0.0f;
        }
    }

    const int    HW   = FS * FS;
    const float* base = feat + (size_t)(bid * C + c0) * HW;
    float*       ob   = out + ((size_t)(n * NI) * C + c0) * (PHh * PWw) + tid;

    // wave slab: feature rows for sample rows 4w..4w+3; x-range padded to 16B groups.
    // FS % 4 == 0 and x0a % 4 == 0  =>  x0a + Wp4 <= FS (no row overrun).
    const int x0     = s_xlo[0];
    const int x0a    = x0 & ~3;
    const int xend   = s_xhi[63] + 1;
    const int Wp4    = (xend - x0a + 3) & ~3;
    const int slabY0 = s_ylo[4 * w];
    const int rowsW  = s_yhi[4 * w + 3] - slabY0 + 1;
    const int slabN4 = rowsW * Wp4;

    if (slabN4 <= SLAB4_MAX) {
        const int K4 = (slabN4 + 255) >> 8;
        const int W4 = Wp4 >> 2;                // 16B groups per row

        int gofs[2];
        {
            const int gmax = (slabN4 >> 2) - 1;
            #pragma unroll
            for (int j = 0; j < 2; ++j) {
                int g = (tid & 63) + j * 64;
                if (g > gmax) g = gmax;          // clamp: duplicate group, dest stays linear
                int row  = g / W4;
                int col4 = g - row * W4;
                gofs[j] = (slabY0 + row) * FS + x0a + (col4 << 2);
            }
        }

        int toff[16];
        #pragma unroll
        for (int k = 0; k < 16; ++k)
            toff[k] = (fr[k] - slabY0) * Wp4 + (fc[k] - x0a);

        float* b0 = &wbuf[w][0][0];
        float* b1 = &wbuf[w][1][0];
        float* b2 = &wbuf[w][2][0];

        if (K4 == 1) run_staged<1>(base, HW, b0, b1, b2, gofs, toff, tw, m, ob);
        else         run_staged<2>(base, HW, b0, b1, b2, gofs, toff, tw, m, ob);
    } else {
        // fallback: direct per-thread gather (rare, x-sparse big rois; wave-uniform branch)
        int gidx[16];
        #pragma unroll
        for (int k = 0; k < 16; ++k) gidx[k] = fr[k] * FS + fc[k];

        for (int cc = 0; cc < CHUNK; ++cc) {
            const float* p = base + (size_t)cc * HW;
            float acc = 0.0f;
            #pragma unroll
            for (int k = 0; k < 16; ++k) acc = fmaf(tw[k], p[gidx[k]], acc);
            #pragma unroll
            for (int i = 0; i < NI; ++i)
                __builtin_nontemporal_store(acc * m[i],
                    &ob[(size_t)((i * C + cc) * (PHh * PWw))]);
        }
    }
}

} // namespace

extern "C" void kernel_launch(void* const* d_in, const int* in_sizes, int n_in,
                              void* d_out, int out_size, void* d_ws, size_t ws_size,
                              hipStream_t stream)
{
    const float* f0   = (const float*)d_in[0];
    const float* f1   = (const float*)d_in[1];
    const float* f2   = (const float*)d_in[2];
    const float* f3   = (const float*)d_in[3];
    const float* rois = (const float*)d_in[4];
    float*       out  = (float*)d_out;

    dim3 grid(NROI, C / CHUNK);
    mia_kernel<<<grid, 256, 0, stream>>>(f0, f1, f2, f3, rois, out);
}